// Round 1
// baseline (608.353 us; speedup 1.0000x reference)
//
#include <hip/hip_runtime.h>
#include <hip/hip_bf16.h>

typedef __bf16 bf16;
typedef __bf16 bf16x4 __attribute__((ext_vector_type(4)));
typedef __bf16 bf16x8 __attribute__((ext_vector_type(8)));
typedef float  f32x4  __attribute__((ext_vector_type(4)));

#define SEQ  2048
#define HID  4096
#define QKVN 6144   // 4096 Q + 1024 K + 1024 V

__device__ __forceinline__ void gload_lds16(const void* g, void* l) {
  __builtin_amdgcn_global_load_lds(
      (const __attribute__((address_space(1))) void*)g,
      (__attribute__((address_space(3))) void*)l, 16, 0, 0);
}

// ---------------- cast f32 -> bf16 (vectorized) ----------------
__global__ __launch_bounds__(256) void cast_f32_bf16(const float* __restrict__ in,
                                                     bf16* __restrict__ out, int n) {
  int i = (blockIdx.x * 256 + threadIdx.x) * 4;
  int stride = gridDim.x * 256 * 4;
  for (; i < n; i += stride) {
    float4 v = *(const float4*)(in + i);
    bf16x4 o;
    o[0] = (bf16)v.x; o[1] = (bf16)v.y; o[2] = (bf16)v.z; o[3] = (bf16)v.w;
    *(bf16x4*)(out + i) = o;
  }
}

// ---------------- tiled transpose + cast: W[4096][N] f32 -> Wt[roff+N][4096] bf16 ----------------
__global__ __launch_bounds__(256) void transpose_cast(const float* __restrict__ W,
                                                      bf16* __restrict__ Wt,
                                                      int N, int roff) {
  __shared__ float tile[32][33];
  int k0 = blockIdx.y * 32;
  int n0 = blockIdx.x * 32;
  int t = threadIdx.x;
  int r = t >> 5, c = t & 31;
#pragma unroll
  for (int p = 0; p < 4; ++p)
    tile[r + p * 8][c] = W[(size_t)(k0 + r + p * 8) * N + n0 + c];
  __syncthreads();
#pragma unroll
  for (int p = 0; p < 4; ++p)
    Wt[(size_t)(roff + n0 + r + p * 8) * 4096 + k0 + c] = (bf16)tile[c][r + p * 8];
}

// ---------------- m97-style 128x128 GEMM, A[M,K] @ Bt[N,K]^T -> C[M,ldc] ----------------
template <typename OUT_T>
__global__ __launch_bounds__(256) void gemm_bt(const bf16* __restrict__ A,
                                               const bf16* __restrict__ Bt,
                                               OUT_T* __restrict__ C,
                                               int K, int ldc) {
  __shared__ __align__(16) bf16 Abuf[128 * 32];
  __shared__ __align__(16) bf16 Bbuf[128 * 32];
  int m0 = blockIdx.y * 128, n0 = blockIdx.x * 128;
  int tid = threadIdx.x, w = tid >> 6, lane = tid & 63;
  int wr = w >> 1, wc = w & 1;
  int l15 = lane & 15, l4 = lane >> 4;
  f32x4 acc[4][4] = {};
  const int nk = K >> 5;
  for (int kt = 0; kt < nk; ++kt) {
    int k0 = kt << 5;
    // stage A,B tiles (128x32 bf16 each) via async global->LDS, 16B/lane
#pragma unroll
    for (int p = 0; p < 2; ++p) {
      int elem = p * 2048 + w * 512 + lane * 8;
      int row = elem >> 5, col = elem & 31;
      gload_lds16(A + (size_t)(m0 + row) * K + k0 + col, (char*)Abuf + 2 * elem);
      gload_lds16(Bt + (size_t)(n0 + row) * K + k0 + col, (char*)Bbuf + 2 * elem);
    }
    __syncthreads();
    bf16x8 af[4], bfr[4];
#pragma unroll
    for (int m = 0; m < 4; ++m)
      af[m] = *(const bf16x8*)(Abuf + (wr * 64 + m * 16 + l15) * 32 + l4 * 8);
#pragma unroll
    for (int n = 0; n < 4; ++n)
      bfr[n] = *(const bf16x8*)(Bbuf + (wc * 64 + n * 16 + l15) * 32 + l4 * 8);
#pragma unroll
    for (int m = 0; m < 4; ++m)
#pragma unroll
      for (int n = 0; n < 4; ++n)
        acc[m][n] = __builtin_amdgcn_mfma_f32_16x16x32_bf16(af[m], bfr[n], acc[m][n], 0, 0, 0);
    __syncthreads();
  }
#pragma unroll
  for (int m = 0; m < 4; ++m)
#pragma unroll
    for (int n = 0; n < 4; ++n)
#pragma unroll
      for (int i = 0; i < 4; ++i) {
        int row = m0 + wr * 64 + m * 16 + l4 * 4 + i;
        int col = n0 + wc * 64 + n * 16 + l15;
        C[(size_t)row * ldc + col] = (OUT_T)acc[m][n][i];
      }
}

// ---------------- flash-style causal GQA attention ----------------
// QKV: [SEQ][6144] bf16 (Q at col 0, K at 4096, V at 5120). attn out: [SEQ][4096] bf16.
__global__ __launch_bounds__(256) void attn_kernel(const bf16* __restrict__ QKV,
                                                   bf16* __restrict__ attn) {
  __shared__ __align__(16) bf16 Klds[64 * 128];   // [ks][d], XOR-swizzled via source
  __shared__ __align__(16) bf16 Vt[128 * 64];     // [d][ks], XOR-swizzled
  __shared__ __align__(16) bf16 Plds[4 * 16 * 64];// per-wave [16 q][64 ks], XOR-swizzled
  const int h = blockIdx.y;
  const int qb = blockIdx.x;
  const int q0 = qb * 64;
  const int tid = threadIdx.x, w = tid >> 6, lane = tid & 63;
  const int l15 = lane & 15, l4 = lane >> 4;
  const int wq0 = q0 + w * 16;
  const int qcol = h * 128;
  const int kcol = 4096 + (h >> 2) * 128;
  const int vcol = 5120 + (h >> 2) * 128;
  const float scale = 0.08838834764831845f;  // 1/sqrt(128)
  const float LOG2E = 1.4426950408889634f;

  // hoist Q fragments (16 rows x 128 d per wave)
  bf16x8 aq[4];
#pragma unroll
  for (int kc = 0; kc < 4; ++kc)
    aq[kc] = *(const bf16x8*)(QKV + (size_t)(wq0 + l15) * QKVN + qcol + kc * 32 + l4 * 8);

  f32x4 acc_o[8] = {};
  float mrow[4], lrow[4];
#pragma unroll
  for (int i = 0; i < 4; ++i) { mrow[i] = -1e30f; lrow[i] = 0.f; }

  const int nkb = qb + 1;
  for (int kbi = 0; kbi < nkb; ++kbi) {
    int kb = kbi * 64;
    // ---- stage K tile [64][128] linear LDS, swizzled global source ----
#pragma unroll
    for (int p = 0; p < 4; ++p) {
      int chunk = (p * 4 + w) * 64 + lane;
      int elem = chunk * 8;
      int row = elem >> 7;
      int colb = (elem & 127) * 2;
      int scol = colb ^ ((row & 7) << 4);
      const char* src = (const char*)QKV + ((size_t)(kb + row) * QKVN + kcol) * 2 + scol;
      gload_lds16(src, (char*)Klds + elem * 2);
    }
    // ---- stage V transposed: Vt[d][ks], swizzled ----
#pragma unroll
    for (int p = 0; p < 16; ++p) {
      int pi = p * 256 + tid;           // 0..4095
      int d2 = pi & 63, kp = pi >> 6;   // d pair, ks
      int d = d2 * 2;
      unsigned vv = *(const unsigned*)(QKV + (size_t)(kb + kp) * QKVN + vcol + d);
      int b0 = ((d * 64 + kp) * 2) ^ ((d & 7) << 4);
      int b1 = (((d + 1) * 64 + kp) * 2) ^ (((d + 1) & 7) << 4);
      *(unsigned short*)((char*)Vt + b0) = (unsigned short)(vv & 0xffff);
      *(unsigned short*)((char*)Vt + b1) = (unsigned short)(vv >> 16);
    }
    __syncthreads();
    // ---- QK^T: S[16 q][64 ks] per wave ----
    f32x4 accs[4] = {};
#pragma unroll
    for (int n = 0; n < 4; ++n) {
      int row_ = n * 16 + l15;
      int sw = (row_ & 7) << 4;
#pragma unroll
      for (int kc = 0; kc < 4; ++kc) {
        bf16x8 bk = *(const bf16x8*)((const char*)Klds + row_ * 256 + ((kc * 64 + l4 * 16) ^ sw));
        accs[n] = __builtin_amdgcn_mfma_f32_16x16x32_bf16(aq[kc], bk, accs[n], 0, 0, 0);
      }
    }
    // ---- scale + causal mask ----
    bool needmask = (kb + 64 > wq0);
    float s[4][4];
#pragma unroll
    for (int n = 0; n < 4; ++n)
#pragma unroll
      for (int i = 0; i < 4; ++i) {
        float v = accs[n][i] * scale;
        if (needmask) {
          int ks = kb + n * 16 + l15;
          int qr = wq0 + l4 * 4 + i;
          if (ks > qr) v = -1e30f;
        }
        s[n][i] = v;
      }
    // ---- online softmax update ----
    float fac[4], ps[4][4];
#pragma unroll
    for (int i = 0; i < 4; ++i) {
      float t = fmaxf(fmaxf(s[0][i], s[1][i]), fmaxf(s[2][i], s[3][i]));
      t = fmaxf(t, __shfl_xor(t, 1));
      t = fmaxf(t, __shfl_xor(t, 2));
      t = fmaxf(t, __shfl_xor(t, 4));
      t = fmaxf(t, __shfl_xor(t, 8));
      float mnew = fmaxf(mrow[i], t);
      fac[i] = exp2f((mrow[i] - mnew) * LOG2E);
      float psum = 0.f;
#pragma unroll
      for (int n = 0; n < 4; ++n) {
        float p = exp2f((s[n][i] - mnew) * LOG2E);
        ps[n][i] = p; psum += p;
      }
      psum += __shfl_xor(psum, 1);
      psum += __shfl_xor(psum, 2);
      psum += __shfl_xor(psum, 4);
      psum += __shfl_xor(psum, 8);
      lrow[i] = lrow[i] * fac[i] + psum;
      mrow[i] = mnew;
    }
#pragma unroll
    for (int n2 = 0; n2 < 8; ++n2)
#pragma unroll
      for (int i = 0; i < 4; ++i)
        acc_o[n2][i] *= fac[i];
    // ---- write P (per-wave region, swizzled) ----
    char* Pw = (char*)Plds + w * 2048;
#pragma unroll
    for (int n = 0; n < 4; ++n)
#pragma unroll
      for (int i = 0; i < 4; ++i) {
        int r = l4 * 4 + i;
        int b = (r * 128 + (n * 16 + l15) * 2) ^ ((r & 7) << 4);
        *(bf16*)(Pw + b) = (bf16)ps[n][i];
      }
    // prevent compile-time reordering of P reads before P writes (DS is in-order per wave in HW)
    __builtin_amdgcn_sched_barrier(0);
    asm volatile("" ::: "memory");
    // ---- PV: out += P @ V ----
    bf16x8 pa[2];
#pragma unroll
    for (int kc = 0; kc < 2; ++kc)
      pa[kc] = *(const bf16x8*)(Pw + (l15 * 128 + ((kc * 64 + l4 * 16) ^ ((l15 & 7) << 4))));
#pragma unroll
    for (int n2 = 0; n2 < 8; ++n2) {
      int row_ = n2 * 16 + l15;
      int sw = (row_ & 7) << 4;
#pragma unroll
      for (int kc = 0; kc < 2; ++kc) {
        bf16x8 bv = *(const bf16x8*)((const char*)Vt + row_ * 128 + ((kc * 64 + l4 * 16) ^ sw));
        acc_o[n2] = __builtin_amdgcn_mfma_f32_16x16x32_bf16(pa[kc], bv, acc_o[n2], 0, 0, 0);
      }
    }
    __syncthreads();
  }
  // ---- epilogue: out = acc_o / l ----
#pragma unroll
  for (int n2 = 0; n2 < 8; ++n2)
#pragma unroll
    for (int i = 0; i < 4; ++i) {
      int row = wq0 + l4 * 4 + i;
      int col = h * 128 + n2 * 16 + l15;
      attn[(size_t)row * 4096 + col] = (bf16)(acc_o[n2][i] / lrow[i]);
    }
}

extern "C" void kernel_launch(void* const* d_in, const int* in_sizes, int n_in,
                              void* d_out, int out_size, void* d_ws, size_t ws_size,
                              hipStream_t stream) {
  const float* X  = (const float*)d_in[0];
  const float* Wq = (const float*)d_in[1];
  const float* Wk = (const float*)d_in[2];
  const float* Wv = (const float*)d_in[3];
  const float* Wo = (const float*)d_in[4];
  float* out = (float*)d_out;

  // workspace layout (with reuse): total 92,274,688 bytes
  const size_t XB_OFF  = 0;                       // 2048*4096*2 = 16.78 MB (later: attn out)
  const size_t WT_OFF  = 16777216;                // 6144*4096*2 = 50.33 MB (later: Wo^T)
  const size_t QKV_OFF = 16777216 + 50331648;     // 2048*6144*2 = 25.17 MB
  if (ws_size < (size_t)92274688) return;  // insufficient scratch; bail cleanly

  char* ws = (char*)d_ws;
  bf16* Xb    = (bf16*)(ws + XB_OFF);
  bf16* Wt    = (bf16*)(ws + WT_OFF);
  bf16* QKV   = (bf16*)(ws + QKV_OFF);
  bf16* attnb = Xb;  // reuse after gemm1 consumed Xb

  // 1. cast hidden states
  cast_f32_bf16<<<2048, 256, 0, stream>>>(X, Xb, SEQ * HID);
  // 2. transpose-cast Wq/Wk/Wv into fused [6144][4096] B^T
  transpose_cast<<<dim3(4096 / 32, 4096 / 32), 256, 0, stream>>>(Wq, Wt, 4096, 0);
  transpose_cast<<<dim3(1024 / 32, 4096 / 32), 256, 0, stream>>>(Wk, Wt, 1024, 4096);
  transpose_cast<<<dim3(1024 / 32, 4096 / 32), 256, 0, stream>>>(Wv, Wt, 1024, 5120);
  // 3. fused QKV projection: [2048,4096] @ [4096,6144]
  gemm_bt<bf16><<<dim3(QKVN / 128, SEQ / 128), 256, 0, stream>>>(Xb, Wt, QKV, HID, QKVN);
  // 4. transpose-cast Wo (reuses Wt space; stream-ordered after gemm1)
  transpose_cast<<<dim3(4096 / 32, 4096 / 32), 256, 0, stream>>>(Wo, Wt, 4096, 0);
  // 5. causal GQA flash attention
  attn_kernel<<<dim3(SEQ / 64, 32), 256, 0, stream>>>(QKV, attnb);
  // 6. output projection -> f32 out: [2048,4096] @ [4096,4096]
  gemm_bt<float><<<dim3(4096 / 128, SEQ / 128), 256, 0, stream>>>(attnb, Wt, out, HID, 4096);
}

// Round 2
// 440.539 us; speedup vs baseline: 1.3809x; 1.3809x over previous
//
#include <hip/hip_runtime.h>
#include <hip/hip_bf16.h>

typedef __bf16 bf16;
typedef __bf16 bf16x4 __attribute__((ext_vector_type(4)));
typedef __bf16 bf16x8 __attribute__((ext_vector_type(8)));
typedef float  f32x4  __attribute__((ext_vector_type(4)));

#define SEQ  2048
#define HID  4096
#define QKVN 6144   // 4096 Q + 1024 K + 1024 V

__device__ __forceinline__ void gload_lds16(const void* g, void* l) {
  __builtin_amdgcn_global_load_lds(
      (const __attribute__((address_space(1))) void*)g,
      (__attribute__((address_space(3))) void*)l, 16, 0, 0);
}

// ---------------- cast f32 -> bf16 (vectorized) ----------------
__global__ __launch_bounds__(256) void cast_f32_bf16(const float* __restrict__ in,
                                                     bf16* __restrict__ out, int n) {
  int i = (blockIdx.x * 256 + threadIdx.x) * 4;
  int stride = gridDim.x * 256 * 4;
  for (; i < n; i += stride) {
    float4 v = *(const float4*)(in + i);
    bf16x4 o;
    o[0] = (bf16)v.x; o[1] = (bf16)v.y; o[2] = (bf16)v.z; o[3] = (bf16)v.w;
    *(bf16x4*)(out + i) = o;
  }
}

// ---------------- tiled transpose + cast: W[4096][N] f32 -> Wt[roff+N][4096] bf16 ----------------
__global__ __launch_bounds__(256) void transpose_cast(const float* __restrict__ W,
                                                      bf16* __restrict__ Wt,
                                                      int N, int roff) {
  __shared__ float tile[32][33];
  int k0 = blockIdx.y * 32;
  int n0 = blockIdx.x * 32;
  int t = threadIdx.x;
  int r = t >> 5, c = t & 31;
#pragma unroll
  for (int p = 0; p < 4; ++p)
    tile[r + p * 8][c] = W[(size_t)(k0 + r + p * 8) * N + n0 + c];
  __syncthreads();
#pragma unroll
  for (int p = 0; p < 4; ++p)
    Wt[(size_t)(roff + n0 + r + p * 8) * 4096 + k0 + c] = (bf16)tile[c][r + p * 8];
}

// ---------------- transpose V out of QKV into global: Vt_g[g][d][s] ----------------
// QKV: [SEQ][6144], V cols at 5120 + g*128. Output: Vt_g[(g*128 + d)*SEQ + s].
__global__ __launch_bounds__(256) void transpose_v(const bf16* __restrict__ QKV,
                                                   bf16* __restrict__ Vt_g) {
  __shared__ bf16 tile[32][33];
  int s0 = blockIdx.x * 32;          // seq tile
  int d0 = blockIdx.y * 32;          // head-dim tile
  int g  = blockIdx.z;               // kv head
  int t = threadIdx.x;
  int r = t >> 5, c = t & 31;
#pragma unroll
  for (int p = 0; p < 4; ++p)
    tile[r + p * 8][c] = QKV[(size_t)(s0 + r + p * 8) * QKVN + 5120 + g * 128 + d0 + c];
  __syncthreads();
#pragma unroll
  for (int p = 0; p < 4; ++p)
    Vt_g[(size_t)(g * 128 + d0 + r + p * 8) * SEQ + s0 + c] = tile[c][r + p * 8];
}

// ---------------- m97-style 128x128 GEMM, A[M,K] @ Bt[N,K]^T -> C[M,ldc] ----------------
template <typename OUT_T>
__global__ __launch_bounds__(256) void gemm_bt(const bf16* __restrict__ A,
                                               const bf16* __restrict__ Bt,
                                               OUT_T* __restrict__ C,
                                               int K, int ldc) {
  __shared__ __align__(16) bf16 Abuf[128 * 32];
  __shared__ __align__(16) bf16 Bbuf[128 * 32];
  int m0 = blockIdx.y * 128, n0 = blockIdx.x * 128;
  int tid = threadIdx.x, w = tid >> 6, lane = tid & 63;
  int wr = w >> 1, wc = w & 1;
  int l15 = lane & 15, l4 = lane >> 4;
  f32x4 acc[4][4] = {};
  const int nk = K >> 5;
  for (int kt = 0; kt < nk; ++kt) {
    int k0 = kt << 5;
#pragma unroll
    for (int p = 0; p < 2; ++p) {
      int elem = p * 2048 + w * 512 + lane * 8;
      int row = elem >> 5, col = elem & 31;
      gload_lds16(A + (size_t)(m0 + row) * K + k0 + col, (char*)Abuf + 2 * elem);
      gload_lds16(Bt + (size_t)(n0 + row) * K + k0 + col, (char*)Bbuf + 2 * elem);
    }
    __syncthreads();
    bf16x8 af[4], bfr[4];
#pragma unroll
    for (int m = 0; m < 4; ++m)
      af[m] = *(const bf16x8*)(Abuf + (wr * 64 + m * 16 + l15) * 32 + l4 * 8);
#pragma unroll
    for (int n = 0; n < 4; ++n)
      bfr[n] = *(const bf16x8*)(Bbuf + (wc * 64 + n * 16 + l15) * 32 + l4 * 8);
#pragma unroll
    for (int m = 0; m < 4; ++m)
#pragma unroll
      for (int n = 0; n < 4; ++n)
        acc[m][n] = __builtin_amdgcn_mfma_f32_16x16x32_bf16(af[m], bfr[n], acc[m][n], 0, 0, 0);
    __syncthreads();
  }
#pragma unroll
  for (int m = 0; m < 4; ++m)
#pragma unroll
    for (int n = 0; n < 4; ++n)
#pragma unroll
      for (int i = 0; i < 4; ++i) {
        int row = m0 + wr * 64 + m * 16 + l4 * 4 + i;
        int col = n0 + wc * 64 + n * 16 + l15;
        C[(size_t)row * ldc + col] = (OUT_T)acc[m][n][i];
      }
}

// ---------------- flash-style causal GQA attention ----------------
// QKV: [SEQ][6144] bf16 (Q at 0, K at 4096+g*128). Vt_g: [g][128][SEQ].
// Grid: 1024 blocks 1-D. bid&7 = kv-head (XCD locality: K/V of one kv-head ~1MB -> one XCD L2).
// qb spread so each CU's resident blocks get qb {q, q+8, q+16, q+24} (balanced causal work).
__global__ __launch_bounds__(256) void attn_kernel(const bf16* __restrict__ QKV,
                                                   const bf16* __restrict__ Vt_g,
                                                   bf16* __restrict__ attn) {
  __shared__ __align__(16) bf16 Klds[64 * 128];   // [ks][d], XOR-swizzled (slot ^= row&7)
  __shared__ __align__(16) bf16 Vlds[128 * 64];   // [d][ks], XOR-swizzled (slot ^= row&7)
  __shared__ __align__(16) bf16 Plds[4 * 16 * 64];// per-wave [16 q][64 ks], XOR-swizzled
  const int bid = blockIdx.x;
  const int g = bid & 7;             // kv head
  const int slot_ = bid >> 3;
  const int h = g * 4 + (slot_ & 3); // q head
  const int qb = slot_ >> 2;
  const int q0 = qb * 64;
  const int tid = threadIdx.x, w = tid >> 6, lane = tid & 63;
  const int l15 = lane & 15, l4 = lane >> 4;
  const int wq0 = q0 + w * 16;
  const int qcol = h * 128;
  const int kcol = 4096 + g * 128;
  const float scale = 0.08838834764831845f;  // 1/sqrt(128)
  const float LOG2E = 1.4426950408889634f;

  // hoist Q fragments (16 rows x 128 d per wave)
  bf16x8 aq[4];
#pragma unroll
  for (int kc = 0; kc < 4; ++kc)
    aq[kc] = *(const bf16x8*)(QKV + (size_t)(wq0 + l15) * QKVN + qcol + kc * 32 + l4 * 8);

  f32x4 acc_o[8] = {};
  float mrow[4], lrow[4];
#pragma unroll
  for (int i = 0; i < 4; ++i) { mrow[i] = -1e30f; lrow[i] = 0.f; }

  const bf16* Vhead = Vt_g + (size_t)g * 128 * SEQ;

  const int nkb = qb + 1;
  for (int kbi = 0; kbi < nkb; ++kbi) {
    int kb = kbi * 64;
    // ---- stage K tile [64 ks][128 d] + V tile [128 d][64 ks], both via async
    //      global->LDS 16B/lane with pre-swizzled global source (rule #21) ----
#pragma unroll
    for (int p = 0; p < 4; ++p) {
      // K: chunk c in [0,1024): row = c>>4 (ks), slot = c&15 (16B of 8 d)
      int ck = p * 256 + tid;
      int krow = ck >> 4, kslot = ck & 15;
      int ksl = kslot ^ (krow & 7);
      gload_lds16((const char*)(QKV + (size_t)(kb + krow) * QKVN + kcol) + ksl * 16,
                  (char*)Klds + ck * 16);
      // V: chunk c in [0,1024): row = c>>3 (d), slot = c&7 (16B of 8 ks)
      int cv = p * 256 + tid;
      int vrow = cv >> 3, vslot = cv & 7;
      int vsl = vslot ^ (vrow & 7);
      gload_lds16(Vhead + (size_t)vrow * SEQ + kb + vsl * 8,
                  (char*)Vlds + cv * 16);
    }
    __syncthreads();
    // ---- QK^T: S[16 q][64 ks] per wave ----
    f32x4 accs[4] = {};
#pragma unroll
    for (int n = 0; n < 4; ++n) {
      int row_ = n * 16 + l15;
      int sw = (row_ & 7) << 4;
#pragma unroll
      for (int kc = 0; kc < 4; ++kc) {
        bf16x8 bk = *(const bf16x8*)((const char*)Klds + row_ * 256 + ((kc * 64 + l4 * 16) ^ sw));
        accs[n] = __builtin_amdgcn_mfma_f32_16x16x32_bf16(aq[kc], bk, accs[n], 0, 0, 0);
      }
    }
    // ---- scale + causal mask ----
    bool needmask = (kb + 64 > wq0);
    float s[4][4];
#pragma unroll
    for (int n = 0; n < 4; ++n)
#pragma unroll
      for (int i = 0; i < 4; ++i) {
        float v = accs[n][i] * scale;
        if (needmask) {
          int ks = kb + n * 16 + l15;
          int qr = wq0 + l4 * 4 + i;
          if (ks > qr) v = -1e30f;
        }
        s[n][i] = v;
      }
    // ---- online softmax update ----
    float fac[4], ps[4][4];
#pragma unroll
    for (int i = 0; i < 4; ++i) {
      float t = fmaxf(fmaxf(s[0][i], s[1][i]), fmaxf(s[2][i], s[3][i]));
      t = fmaxf(t, __shfl_xor(t, 1));
      t = fmaxf(t, __shfl_xor(t, 2));
      t = fmaxf(t, __shfl_xor(t, 4));
      t = fmaxf(t, __shfl_xor(t, 8));
      float mnew = fmaxf(mrow[i], t);
      fac[i] = exp2f((mrow[i] - mnew) * LOG2E);
      float psum = 0.f;
#pragma unroll
      for (int n = 0; n < 4; ++n) {
        float p = exp2f((s[n][i] - mnew) * LOG2E);
        ps[n][i] = p; psum += p;
      }
      psum += __shfl_xor(psum, 1);
      psum += __shfl_xor(psum, 2);
      psum += __shfl_xor(psum, 4);
      psum += __shfl_xor(psum, 8);
      lrow[i] = lrow[i] * fac[i] + psum;
      mrow[i] = mnew;
    }
#pragma unroll
    for (int n2 = 0; n2 < 8; ++n2)
#pragma unroll
      for (int i = 0; i < 4; ++i)
        acc_o[n2][i] *= fac[i];
    // ---- write P (per-wave region, swizzled) ----
    char* Pw = (char*)Plds + w * 2048;
#pragma unroll
    for (int n = 0; n < 4; ++n)
#pragma unroll
      for (int i = 0; i < 4; ++i) {
        int r = l4 * 4 + i;
        int b = (r * 128 + (n * 16 + l15) * 2) ^ ((r & 7) << 4);
        *(bf16*)(Pw + b) = (bf16)ps[n][i];
      }
    // prevent compile-time reordering of P reads before P writes (DS is in-order per wave in HW)
    __builtin_amdgcn_sched_barrier(0);
    asm volatile("" ::: "memory");
    // ---- PV: out += P @ V ----
    bf16x8 pa[2];
#pragma unroll
    for (int kc = 0; kc < 2; ++kc)
      pa[kc] = *(const bf16x8*)(Pw + (l15 * 128 + ((kc * 64 + l4 * 16) ^ ((l15 & 7) << 4))));
#pragma unroll
    for (int n2 = 0; n2 < 8; ++n2) {
      int row_ = n2 * 16 + l15;
      int sw = (row_ & 7) << 4;
#pragma unroll
      for (int kc = 0; kc < 2; ++kc) {
        bf16x8 bv = *(const bf16x8*)((const char*)Vlds + row_ * 128 + ((kc * 64 + l4 * 16) ^ sw));
        acc_o[n2] = __builtin_amdgcn_mfma_f32_16x16x32_bf16(pa[kc], bv, acc_o[n2], 0, 0, 0);
      }
    }
    __syncthreads();
  }
  // ---- epilogue: out = acc_o / l ----
#pragma unroll
  for (int n2 = 0; n2 < 8; ++n2)
#pragma unroll
    for (int i = 0; i < 4; ++i) {
      int row = wq0 + l4 * 4 + i;
      int col = h * 128 + n2 * 16 + l15;
      attn[(size_t)row * 4096 + col] = (bf16)(acc_o[n2][i] / lrow[i]);
    }
}

extern "C" void kernel_launch(void* const* d_in, const int* in_sizes, int n_in,
                              void* d_out, int out_size, void* d_ws, size_t ws_size,
                              hipStream_t stream) {
  const float* X  = (const float*)d_in[0];
  const float* Wq = (const float*)d_in[1];
  const float* Wk = (const float*)d_in[2];
  const float* Wv = (const float*)d_in[3];
  const float* Wo = (const float*)d_in[4];
  float* out = (float*)d_out;

  // workspace layout (with reuse): total 92,274,688 bytes
  //  [0, 16.78MB)        Xb (bf16 X)           -> later reused as attn output
  //  [16.78, 67.11MB)    Wt (QKV^T weights)    -> later first 33.55MB = Wo^T,
  //                                               bytes [50.33,54.53MB) = Vt_g (4MB)
  //  [67.11, 92.27MB)    QKV activations
  const size_t XB_OFF  = 0;
  const size_t WT_OFF  = 16777216;
  const size_t VT_OFF  = WT_OFF + 33554432;       // inside Wt region, past Wo^T
  const size_t QKV_OFF = 16777216 + 50331648;
  if (ws_size < (size_t)92274688) return;

  char* ws = (char*)d_ws;
  bf16* Xb    = (bf16*)(ws + XB_OFF);
  bf16* Wt    = (bf16*)(ws + WT_OFF);
  bf16* Vt_g  = (bf16*)(ws + VT_OFF);
  bf16* QKV   = (bf16*)(ws + QKV_OFF);
  bf16* attnb = Xb;  // reuse after gemm1 consumed Xb

  // 1. cast hidden states
  cast_f32_bf16<<<2048, 256, 0, stream>>>(X, Xb, SEQ * HID);
  // 2. transpose-cast Wq/Wk/Wv into fused [6144][4096] B^T
  transpose_cast<<<dim3(4096 / 32, 4096 / 32), 256, 0, stream>>>(Wq, Wt, 4096, 0);
  transpose_cast<<<dim3(1024 / 32, 4096 / 32), 256, 0, stream>>>(Wk, Wt, 1024, 4096);
  transpose_cast<<<dim3(1024 / 32, 4096 / 32), 256, 0, stream>>>(Wv, Wt, 1024, 5120);
  // 3. fused QKV projection: [2048,4096] @ [4096,6144]
  gemm_bt<bf16><<<dim3(QKVN / 128, SEQ / 128), 256, 0, stream>>>(Xb, Wt, QKV, HID, QKVN);
  // 4. transpose-cast Wo (reuses Wt space) + transpose V into global [g][d][s]
  transpose_cast<<<dim3(4096 / 32, 4096 / 32), 256, 0, stream>>>(Wo, Wt, 4096, 0);
  transpose_v<<<dim3(SEQ / 32, 4, 8), 256, 0, stream>>>(QKV, Vt_g);
  // 5. causal GQA flash attention (balanced + XCD-aware 1-D grid)
  attn_kernel<<<1024, 256, 0, stream>>>(QKV, Vt_g, attnb);
  // 6. output projection -> f32 out: [2048,4096] @ [4096,4096]
  gemm_bt<float><<<dim3(4096 / 128, SEQ / 128), 256, 0, stream>>>(attnb, Wt, out, HID, 4096);
}